// Round 13
// baseline (223.936 us; speedup 1.0000x reference)
//
#include <hip/hip_runtime.h>

typedef float f32x4 __attribute__((ext_vector_type(4)));

// Problem shape (fixed by setup_inputs): B=64, C=1024, H*W=1024, M=768.
#define NB 64
#define NC 1024
#define HW 1024
#define HW4 256          // HW / 4
#define CCH 16           // channel splits in the GEMV
#define CPC (NC / CCH)   // 64 channels per split
#define CGRP 64          // channel groups in apply
#define CPG (NC / CGRP)  // 16 channels per group

// Kernel A: split-K GEMV, stream-structured. Block (cg, b); thread t owns
// hw4 = t; inner loop over CPC channels is base += HW4, load f32x4, fma.
__global__ void __launch_bounds__(256)
adl_gemv(const float* __restrict__ fm,
         const float* __restrict__ w,
         float* __restrict__ partial) {
    const int cg = blockIdx.x;               // 0..CCH-1
    const int b  = blockIdx.y;               // 0..NB-1
    const int t  = threadIdx.x;              // 0..255 == hw4
    const f32x4* fm4 = (const f32x4*)fm;
    const int cbase = cg * CPC;
    size_t base = ((size_t)(b * NC + cbase)) * HW4 + t;
    f32x4 acc = {0.f, 0.f, 0.f, 0.f};
    #pragma unroll 8
    for (int ci = 0; ci < CPC; ++ci) {
        acc += fm4[base] * w[cbase + ci];    // w: wave-uniform s_load
        base += HW4;
    }
    ((f32x4*)partial)[((size_t)(cg * NB + b)) * HW4 + t] = acc;
}

// Kernel B: reduce partials -> logit, sigmoid -> attn output, exact top-M
// drop mask via per-element descending rank with index tie-break (matches
// lax.top_k). Rank on the LOGIT (sigmoid strictly monotone). Grid (4, NB).
__global__ void __launch_bounds__(256)
adl_topk_mask(const float* __restrict__ partial,
              const float* __restrict__ conv_b,
              const int* __restrict__ Mptr,
              float* __restrict__ attn_out,
              float* __restrict__ mask) {
    __shared__ f32x4 s_sh4[HW4];
    float* s_sh = (float*)s_sh4;
    const int slice = blockIdx.x;            // 0..3
    const int b     = blockIdx.y;            // 0..NB-1
    const int tid   = threadIdx.x;           // 0..255
    const float bias = conv_b[0];
    #pragma unroll
    for (int q = 0; q < 4; ++q) {
        const int t = q * 256 + tid;
        float s = bias;
        #pragma unroll 8
        for (int k = 0; k < CCH; ++k)
            s += partial[((size_t)(k * NB + b)) * HW + t];
        s_sh[t] = s;
    }
    __syncthreads();
    const int t = slice * 256 + tid;         // this thread's element
    const float sv = s_sh[t];
    const int M = *Mptr;
    int r = 0;
    #pragma unroll 4
    for (int j4 = 0; j4 < HW4; ++j4) {
        const f32x4 v = s_sh4[j4];           // broadcast LDS read
        const int j = j4 * 4;
        r += (v.x > sv) || (v.x == sv && (j + 0) < t);
        r += (v.y > sv) || (v.y == sv && (j + 1) < t);
        r += (v.z > sv) || (v.z == sv && (j + 2) < t);
        r += (v.w > sv) || (v.w == sv && (j + 3) < t);
    }
    attn_out[(size_t)b * HW + t] = 1.0f / (1.0f + expf(-sv));
    mask[(size_t)b * HW + t] = (r < M) ? 0.0f : 1.0f;
}

// Kernel C: out = fm * mask. ROUND-13 DIAGNOSTIC: body runs TWICE (identical
// addresses/values — idempotent, output unchanged) so this dispatch's duration
// doubles past the harness fills and surfaces in the rocprof top-5 with its
// own FETCH/WRITE/hbm_gbps. Rep 2 re-streams fm after rep 1 fully cycled L3,
// so both reps run at the same (cold) rate: dispatch_dur = 2 x T_apply.
__global__ void __launch_bounds__(256)
adl_apply(const float* __restrict__ fm,
          const float* __restrict__ mask,
          float* __restrict__ out) {
    const int cg = blockIdx.x;               // 0..CGRP-1
    const int b  = blockIdx.y;               // 0..NB-1
    const int t  = threadIdx.x;              // 0..255 == hw4
    const f32x4* fm4   = (const f32x4*)fm;
    const f32x4* mask4 = (const f32x4*)mask;
    f32x4* out4        = (f32x4*)out;
    const f32x4 m = mask4[b * HW4 + t];
    const size_t base0 = ((size_t)(b * NC + cg * CPG)) * HW4 + t;
    #pragma unroll 1
    for (int rep = 0; rep < 2; ++rep) {
        size_t base = base0;
        #pragma unroll 1
        for (int g = 0; g < CPG / 8; ++g) {  // 2 groups of 8 channels
            f32x4 v[8];
            #pragma unroll
            for (int k = 0; k < 8; ++k)
                v[k] = fm4[base + (size_t)k * HW4];
            #pragma unroll
            for (int k = 0; k < 8; ++k)
                __builtin_nontemporal_store(v[k] * m, &out4[base + (size_t)k * HW4]);
            base += (size_t)8 * HW4;
        }
    }
}

extern "C" void kernel_launch(void* const* d_in, const int* in_sizes, int n_in,
                              void* d_out, int out_size, void* d_ws, size_t ws_size,
                              hipStream_t stream) {
    const float* fm   = (const float*)d_in[0];   // [64,1024,32,32] f32
    const float* w    = (const float*)d_in[1];   // [1024] f32
    const float* bias = (const float*)d_in[2];   // [1] f32
    const int*   Mptr = (const int*)d_in[3];     // scalar int (768)

    float* out      = (float*)d_out;                       // dropped [B,C,H,W]
    float* attn_out = out + (size_t)NB * NC * HW;          // attn [B,1,H,W]

    // Workspace: partial [CCH][NB][HW] f32 (4 MB) + mask [NB][HW] f32 (256 KB).
    float* partial = (float*)d_ws;
    float* mask    = partial + (size_t)CCH * NB * HW;

    adl_gemv<<<dim3(CCH, NB), 256, 0, stream>>>(fm, w, partial);
    adl_topk_mask<<<dim3(4, NB), 256, 0, stream>>>(partial, bias, Mptr, attn_out, mask);
    adl_apply<<<dim3(CGRP, NB), 256, 0, stream>>>(fm, mask, out);
}

// Round 14
// 160.886 us; speedup vs baseline: 1.3919x; 1.3919x over previous
//
#include <hip/hip_runtime.h>

typedef float f32x4 __attribute__((ext_vector_type(4)));

// Problem shape (fixed by setup_inputs): B=64, C=1024, H*W=1024, M=768.
#define NB 64
#define NC 1024
#define HW 1024
#define HW4 256          // HW / 4
#define CGRP 64          // channel groups in apply (round-12 best)
#define CPG (NC / CGRP)  // 16 channels per group

// Kernel A: split-K GEMV, stream-structured. Block (cg, b); thread t owns
// hw4 = t; inner loop over CPC channels is base += HW4, load f32x4, fma.
// ROUND-14: CCH 16 -> 32 (2048 blocks, 8/CU, 32 waves/CU) to double the
// outstanding-read depth covering ~900-cyc HBM latency in this pure-read pass.
template<int CCH>
__global__ void __launch_bounds__(256)
adl_gemv(const float* __restrict__ fm,
         const float* __restrict__ w,
         float* __restrict__ partial) {
    constexpr int CPC = NC / CCH;
    const int cg = blockIdx.x;               // 0..CCH-1
    const int b  = blockIdx.y;               // 0..NB-1
    const int t  = threadIdx.x;              // 0..255 == hw4
    const f32x4* fm4 = (const f32x4*)fm;
    const int cbase = cg * CPC;
    size_t base = ((size_t)(b * NC + cbase)) * HW4 + t;
    f32x4 acc = {0.f, 0.f, 0.f, 0.f};
    #pragma unroll 8
    for (int ci = 0; ci < CPC; ++ci) {
        acc += fm4[base] * w[cbase + ci];    // w: wave-uniform s_load
        base += HW4;
    }
    ((f32x4*)partial)[((size_t)(cg * NB + b)) * HW4 + t] = acc;
}

// Kernel B: reduce partials -> logit, sigmoid -> attn output, exact top-M
// drop mask via per-element descending rank with index tie-break (matches
// lax.top_k). Rank on the LOGIT (sigmoid strictly monotone). Grid (4, NB).
template<int CCH>
__global__ void __launch_bounds__(256)
adl_topk_mask(const float* __restrict__ partial,
              const float* __restrict__ conv_b,
              const int* __restrict__ Mptr,
              float* __restrict__ attn_out,
              float* __restrict__ mask) {
    __shared__ f32x4 s_sh4[HW4];
    float* s_sh = (float*)s_sh4;
    const int slice = blockIdx.x;            // 0..3
    const int b     = blockIdx.y;            // 0..NB-1
    const int tid   = threadIdx.x;           // 0..255
    const float bias = conv_b[0];
    #pragma unroll
    for (int q = 0; q < 4; ++q) {
        const int t = q * 256 + tid;
        float s = bias;
        #pragma unroll 8
        for (int k = 0; k < CCH; ++k)
            s += partial[((size_t)(k * NB + b)) * HW + t];
        s_sh[t] = s;
    }
    __syncthreads();
    const int t = slice * 256 + tid;         // this thread's element
    const float sv = s_sh[t];
    const int M = *Mptr;
    int r = 0;
    #pragma unroll 4
    for (int j4 = 0; j4 < HW4; ++j4) {
        const f32x4 v = s_sh4[j4];           // broadcast LDS read
        const int j = j4 * 4;
        r += (v.x > sv) || (v.x == sv && (j + 0) < t);
        r += (v.y > sv) || (v.y == sv && (j + 1) < t);
        r += (v.z > sv) || (v.z == sv && (j + 2) < t);
        r += (v.w > sv) || (v.w == sv && (j + 3) < t);
    }
    attn_out[(size_t)b * HW + t] = 1.0f / (1.0f + expf(-sv));
    mask[(size_t)b * HW + t] = (r < M) ? 0.0f : 1.0f;
}

// Kernel C: out = fm * mask (round-12 best form). Thread t owns hw4 = t
// (mask element loop-invariant); 8-wide load/store batches; 4096 blocks;
// NT stores (regular stores cost +25 us; NT load flavor is a null).
__global__ void __launch_bounds__(256)
adl_apply(const float* __restrict__ fm,
          const float* __restrict__ mask,
          float* __restrict__ out) {
    const int cg = blockIdx.x;               // 0..CGRP-1
    const int b  = blockIdx.y;               // 0..NB-1
    const int t  = threadIdx.x;              // 0..255 == hw4
    const f32x4* fm4   = (const f32x4*)fm;
    const f32x4* mask4 = (const f32x4*)mask;
    f32x4* out4        = (f32x4*)out;
    const f32x4 m = mask4[b * HW4 + t];
    size_t base = ((size_t)(b * NC + cg * CPG)) * HW4 + t;
    #pragma unroll 1
    for (int g = 0; g < CPG / 8; ++g) {      // 2 groups of 8 channels
        f32x4 v[8];
        #pragma unroll
        for (int k = 0; k < 8; ++k)
            v[k] = fm4[base + (size_t)k * HW4];
        #pragma unroll
        for (int k = 0; k < 8; ++k)
            __builtin_nontemporal_store(v[k] * m, &out4[base + (size_t)k * HW4]);
        base += (size_t)8 * HW4;
    }
}

extern "C" void kernel_launch(void* const* d_in, const int* in_sizes, int n_in,
                              void* d_out, int out_size, void* d_ws, size_t ws_size,
                              hipStream_t stream) {
    const float* fm   = (const float*)d_in[0];   // [64,1024,32,32] f32
    const float* w    = (const float*)d_in[1];   // [1024] f32
    const float* bias = (const float*)d_in[2];   // [1] f32
    const int*   Mptr = (const int*)d_in[3];     // scalar int (768)

    float* out      = (float*)d_out;                       // dropped [B,C,H,W]
    float* attn_out = out + (size_t)NB * NC * HW;          // attn [B,1,H,W]

    // Workspace: partial [CCH][NB][HW] f32 + mask [NB][HW] f32.
    const size_t need32 = ((size_t)32 * NB * HW + (size_t)NB * HW) * sizeof(float);
    float* partial = (float*)d_ws;

    if (ws_size >= need32) {
        float* mask = partial + (size_t)32 * NB * HW;
        adl_gemv<32><<<dim3(32, NB), 256, 0, stream>>>(fm, w, partial);
        adl_topk_mask<32><<<dim3(4, NB), 256, 0, stream>>>(partial, bias, Mptr, attn_out, mask);
        adl_apply<<<dim3(CGRP, NB), 256, 0, stream>>>(fm, mask, out);
    } else {
        float* mask = partial + (size_t)16 * NB * HW;
        adl_gemv<16><<<dim3(16, NB), 256, 0, stream>>>(fm, w, partial);
        adl_topk_mask<16><<<dim3(4, NB), 256, 0, stream>>>(partial, bias, Mptr, attn_out, mask);
        adl_apply<<<dim3(CGRP, NB), 256, 0, stream>>>(fm, mask, out);
    }
}

// Round 15
// 158.678 us; speedup vs baseline: 1.4113x; 1.0139x over previous
//
#include <hip/hip_runtime.h>

typedef float f32x4 __attribute__((ext_vector_type(4)));

// Problem shape (fixed by setup_inputs): B=64, C=1024, H*W=1024, M=768.
#define NB 64
#define NC 1024
#define HW 1024
#define HW4 256          // HW / 4
#define CCH 16           // channel splits in the GEMV (16 best: r14 null at 32)
#define CPC (NC / CCH)   // 64 channels per split
#define CGRP 64          // channel groups in apply (r12 best)
#define CPG (NC / CGRP)  // 16 channels per group

// ---------------------------------------------------------------------------
// Final structure (best measured: 158.9 us, round 12). Floor accounting at
// measured per-pattern rates: GEMV 268MB pure-read @6.7TB/s = 40us; topk 4us;
// apply 536MB mixed NT-R/W @4.8TB/s = 112us; launch gaps ~3us => ~159us.
// Mechanisms tested and closed: NT vs regular loads (null), NT vs regular
// stores (NT -25us), 8-wide burst batching (null), occupancy sweeps on both
// streams (null), traversal order (regress), coop/spin fusion (regress:
// sync coherence storms), batch chunking (regress), scatter-zero (regress:
// line-density). Traffic floor 804MB is dependency-forced (mask needs the
// complete GEMV before any output can be written).
// ---------------------------------------------------------------------------

// Kernel A: split-K GEMV, stream-structured. Block (cg, b); thread t owns
// hw4 = t; inner loop over CPC channels is base += HW4, load f32x4, fma.
// Fully coalesced 1 KB/wave/instr.
__global__ void __launch_bounds__(256)
adl_gemv(const float* __restrict__ fm,
         const float* __restrict__ w,
         float* __restrict__ partial) {
    const int cg = blockIdx.x;               // 0..CCH-1
    const int b  = blockIdx.y;               // 0..NB-1
    const int t  = threadIdx.x;              // 0..255 == hw4
    const f32x4* fm4 = (const f32x4*)fm;
    const int cbase = cg * CPC;
    size_t base = ((size_t)(b * NC + cbase)) * HW4 + t;
    f32x4 acc = {0.f, 0.f, 0.f, 0.f};
    #pragma unroll 8
    for (int ci = 0; ci < CPC; ++ci) {
        acc += fm4[base] * w[cbase + ci];    // w: wave-uniform s_load
        base += HW4;
    }
    ((f32x4*)partial)[((size_t)(cg * NB + b)) * HW4 + t] = acc;
}

// Kernel B: reduce partials -> logit, sigmoid -> attn output, exact top-M
// drop mask via per-element descending rank with index tie-break (matches
// lax.top_k). Rank on the LOGIT (sigmoid strictly monotone). Grid (4, NB).
__global__ void __launch_bounds__(256)
adl_topk_mask(const float* __restrict__ partial,
              const float* __restrict__ conv_b,
              const int* __restrict__ Mptr,
              float* __restrict__ attn_out,
              float* __restrict__ mask) {
    __shared__ f32x4 s_sh4[HW4];
    float* s_sh = (float*)s_sh4;
    const int slice = blockIdx.x;            // 0..3
    const int b     = blockIdx.y;            // 0..NB-1
    const int tid   = threadIdx.x;           // 0..255
    const float bias = conv_b[0];
    #pragma unroll
    for (int q = 0; q < 4; ++q) {
        const int t = q * 256 + tid;
        float s = bias;
        #pragma unroll 8
        for (int k = 0; k < CCH; ++k)
            s += partial[((size_t)(k * NB + b)) * HW + t];
        s_sh[t] = s;
    }
    __syncthreads();
    const int t = slice * 256 + tid;         // this thread's element
    const float sv = s_sh[t];
    const int M = *Mptr;
    int r = 0;
    #pragma unroll 4
    for (int j4 = 0; j4 < HW4; ++j4) {
        const f32x4 v = s_sh4[j4];           // broadcast LDS read
        const int j = j4 * 4;
        r += (v.x > sv) || (v.x == sv && (j + 0) < t);
        r += (v.y > sv) || (v.y == sv && (j + 1) < t);
        r += (v.z > sv) || (v.z == sv && (j + 2) < t);
        r += (v.w > sv) || (v.w == sv && (j + 3) < t);
    }
    attn_out[(size_t)b * HW + t] = 1.0f / (1.0f + expf(-sv));
    mask[(size_t)b * HW + t] = (r < M) ? 0.0f : 1.0f;
}

// Kernel C: out = fm * mask. Thread t owns hw4 = t (mask element
// loop-invariant); 8-wide load/store batches; 4096 blocks (max waves);
// NT stores (regular stores cost +25us via cache-allocate interference).
__global__ void __launch_bounds__(256)
adl_apply(const float* __restrict__ fm,
          const float* __restrict__ mask,
          float* __restrict__ out) {
    const int cg = blockIdx.x;               // 0..CGRP-1
    const int b  = blockIdx.y;               // 0..NB-1
    const int t  = threadIdx.x;              // 0..255 == hw4
    const f32x4* fm4   = (const f32x4*)fm;
    const f32x4* mask4 = (const f32x4*)mask;
    f32x4* out4        = (f32x4*)out;
    const f32x4 m = mask4[b * HW4 + t];
    size_t base = ((size_t)(b * NC + cg * CPG)) * HW4 + t;
    #pragma unroll 1
    for (int g = 0; g < CPG / 8; ++g) {      // 2 groups of 8 channels
        f32x4 v[8];
        #pragma unroll
        for (int k = 0; k < 8; ++k)
            v[k] = fm4[base + (size_t)k * HW4];
        #pragma unroll
        for (int k = 0; k < 8; ++k)
            __builtin_nontemporal_store(v[k] * m, &out4[base + (size_t)k * HW4]);
        base += (size_t)8 * HW4;
    }
}

extern "C" void kernel_launch(void* const* d_in, const int* in_sizes, int n_in,
                              void* d_out, int out_size, void* d_ws, size_t ws_size,
                              hipStream_t stream) {
    const float* fm   = (const float*)d_in[0];   // [64,1024,32,32] f32
    const float* w    = (const float*)d_in[1];   // [1024] f32
    const float* bias = (const float*)d_in[2];   // [1] f32
    const int*   Mptr = (const int*)d_in[3];     // scalar int (768)

    float* out      = (float*)d_out;                       // dropped [B,C,H,W]
    float* attn_out = out + (size_t)NB * NC * HW;          // attn [B,1,H,W]

    // Workspace: partial [CCH][NB][HW] f32 (4 MB) + mask [NB][HW] f32 (256 KB).
    float* partial = (float*)d_ws;
    float* mask    = partial + (size_t)CCH * NB * HW;

    adl_gemv<<<dim3(CCH, NB), 256, 0, stream>>>(fm, w, partial);
    adl_topk_mask<<<dim3(4, NB), 256, 0, stream>>>(partial, bias, Mptr, attn_out, mask);
    adl_apply<<<dim3(CGRP, NB), 256, 0, stream>>>(fm, mask, out);
}